// Round 8
// baseline (249.153 us; speedup 1.0000x reference)
//
#include <hip/hip_runtime.h>

typedef unsigned short u16;
typedef unsigned int   u32;

#define NN     65536      // nodes = B*L = 8*8192
#define DDIM   128        // feature dim = H*C
#define EE     1048576    // edges (self loop handled inline, not in CSR)
#define NEG_SLOPE 0.2f
#define SUBCAP 768        // per (bucket, xcd-slot) capacity; mean 512

typedef __attribute__((ext_vector_type(8))) short          short8;
typedef __attribute__((ext_vector_type(2))) float          f32x2;
typedef __attribute__((ext_vector_type(4))) float          f32x4;
typedef __attribute__((ext_vector_type(4))) u32            u32x4;

__device__ __forceinline__ float bf2f(u16 b) { return __uint_as_float(((u32)b) << 16); }
__device__ __forceinline__ u16 f2bf(float f) {
  u32 u = __float_as_uint(f);
  u += 0x7FFFu + ((u >> 16) & 1u);   // round-to-nearest-even
  return (u16)(u >> 16);
}
__device__ __forceinline__ f32x2 bfp2f(u32 w) {
  f32x2 r;
  r.x = __uint_as_float(w << 16);
  r.y = __uint_as_float(w & 0xFFFF0000u);
  return r;
}
__device__ __forceinline__ f32x2 pk_max(f32x2 a, f32x2 b) {
  f32x2 r; r.x = fmaxf(a.x, b.x); r.y = fmaxf(a.y, b.y); return r;
}

// ------ init: dtype detect (b0) + W pre-pack (b1) + cursor zero (b2..b9) ----
__global__ void init_misc(const int* __restrict__ ei, u32* __restrict__ mode,
                          const float* __restrict__ Wl, const float* __restrict__ Wr,
                          u16* __restrict__ wpack, u32* __restrict__ cursor) {
  int t = threadIdx.x, b = blockIdx.x;
  if (b == 0) {
    if (t < 64) {
      int nz = (ei[2 * t + 1] != 0) ? 1 : 0;   // int64 storage => high words zero
      unsigned long long bal = __ballot(nz);
      if (t == 0) mode[0] = (bal == 0ull) ? 1u : 0u;   // 1 = int64
    }
    return;
  }
  if (b == 1) {
    if (t >= 128) return;
    int colhalf = t >> 6, lane = t & 63;
    int m16 = lane & 15, quad = lane >> 4;
    for (int ks = 0; ks < 4; ++ks)
      for (int p = 0; p < 8; ++p) {            // p: 0..3 Wl ct, 4..7 Wr ct
        const float* W = (p < 4) ? Wl : Wr;
        int n = colhalf * 64 + (p & 3) * 16 + m16;
        for (int j = 0; j < 8; ++j) {
          int k = ks * 32 + quad * 8 + j;
          wpack[(((((colhalf * 4 + ks) * 8) + p) * 64 + lane) * 8) + j] = f2bf(W[k * DDIM + n]);
        }
      }
    return;
  }
  int i = (b - 2) * 256 + t;
#pragma unroll
  for (int k = 0; k < 16; ++k) cursor[i * 16 + k] = 0;
}

// ---------------- GEMM: xl = x@Wl, xr = x@Wr (bf16 MFMA, fp32 in, bf16 out) -
// 4096 blocks x 16 rows. Wave w: matrix = w>>1 (Wl/Wr), colhalf = w&1.
// Each wave: 16 W-frags (64 VGPR) -> ~4 waves/SIMD; the 4 waves of a block
// read the same 8 KB of A (L1-shared).
__global__ __launch_bounds__(256) void gemm_xlxr(
    const float* __restrict__ x, const u16* __restrict__ wpack,
    u16* __restrict__ xl, u16* __restrict__ xr)
{
  int tid  = threadIdx.x;
  int wave = tid >> 6;
  int lane = tid & 63;
  int m16  = lane & 15;
  int quad = lane >> 4;
  int mat     = wave >> 1;     // 0 = Wl -> xl, 1 = Wr -> xr
  int colhalf = wave & 1;
  int r0 = blockIdx.x * 16;

  const u16* wp = wpack + (size_t)colhalf * (4 * 8 * 64 * 8);
  short8 bfr[4][4];
#pragma unroll
  for (int ks = 0; ks < 4; ++ks)
#pragma unroll
    for (int ct = 0; ct < 4; ++ct)
      bfr[ks][ct] = *(const short8*)(wp + ((size_t)(ks * 8 + mat * 4 + ct) * 64 + lane) * 8);

  f32x4 acc[4] = { {0,0,0,0},{0,0,0,0},{0,0,0,0},{0,0,0,0} };
#pragma unroll
  for (int ks = 0; ks < 4; ++ks) {
    const float* ap = x + (size_t)(r0 + m16) * DDIM + ks * 32 + quad * 8;
    f32x4 a0 = *(const f32x4*)ap;
    f32x4 a1 = *(const f32x4*)(ap + 4);
    short8 a;
#pragma unroll
    for (int c = 0; c < 4; ++c) { a[c] = (short)f2bf(a0[c]); a[4 + c] = (short)f2bf(a1[c]); }
#pragma unroll
    for (int ct = 0; ct < 4; ++ct)
      acc[ct] = __builtin_amdgcn_mfma_f32_16x16x32_bf16(a, bfr[ks][ct], acc[ct], 0, 0, 0);
  }
  u16* outp = mat ? xr : xl;
#pragma unroll
  for (int ct = 0; ct < 4; ++ct) {
    int c = colhalf * 64 + ct * 16 + m16;
#pragma unroll
    for (int rg = 0; rg < 4; ++rg) {
      int r = r0 + quad * 4 + rg;
      outp[(size_t)r * DDIM + c] = f2bf(acc[ct][rg]);
    }
  }
}

// ---------------- CSR build: two-level counting sort ------------------------
__global__ __launch_bounds__(256) void pass1_bin(const int* __restrict__ ei,
                                                 u32* __restrict__ cursor,
                                                 u32* __restrict__ subb,
                                                 const u32* __restrict__ mode)
{
  int base = (blockIdx.x * 256 + threadIdx.x) * 2;   // grid covers EE/2 exactly
  int s0, s1, d0, d1;
  if (mode[0]) {
    const long long* ei64 = (const long long*)ei;
    s0 = (int)ei64[base];      s1 = (int)ei64[base + 1];
    d0 = (int)ei64[EE + base]; d1 = (int)ei64[EE + base + 1];
  } else {
    int2 s = *(const int2*)(ei + base);
    int2 d = *(const int2*)(ei + EE + base);
    s0 = s.x; s1 = s.y; d0 = d.x; d1 = d.y;
  }
  int x = blockIdx.x & 7;
  int sb0 = (d0 >> 8) * 8 + x;
  u32 p0 = atomicAdd(&cursor[sb0 * 16], 1u);
  if (p0 < SUBCAP) subb[(size_t)sb0 * SUBCAP + p0] = ((u32)(d0 & 255) << 16) | (u32)s0;
  int sb1 = (d1 >> 8) * 8 + x;
  u32 p1 = atomicAdd(&cursor[sb1 * 16], 1u);
  if (p1 < SUBCAP) subb[(size_t)sb1 * SUBCAP + p1] = ((u32)(d1 & 255) << 16) | (u32)s1;
}

// pass2: one block per bucket; integrated bucket-total scan, LDS count+scan
// of 256 dsts, coalesced rowptr write, u16 src placement, and degree-ranked
// node permutation (gat waves then get equal-degree nodes -> no idle quarters).
__global__ __launch_bounds__(256) void pass2_build(const u32* __restrict__ cursor,
                                                   const u32* __restrict__ subb,
                                                   u32* __restrict__ rowptr,
                                                   u16* __restrict__ csr,
                                                   u32* __restrict__ perm)
{
  __shared__ u32 sh[256];
  __shared__ u32 cnt[256];
  __shared__ u32 cur[256];
  __shared__ u32 hist[64];
  int b = blockIdx.x, t = threadIdx.x;

  u32 tot = 0;
#pragma unroll
  for (int x = 0; x < 8; ++x) tot += min(cursor[(t * 8 + x) * 16], (u32)SUBCAP);
  sh[t] = tot; cnt[t] = 0;
  if (t < 64) hist[t] = 0;
  __syncthreads();
  for (int off = 1; off < 256; off <<= 1) {
    u32 v = sh[t]; u32 a = (t >= off) ? sh[t - off] : 0u;
    __syncthreads(); sh[t] = v + a; __syncthreads();
  }
  u32 base      = (b == 0) ? 0u : sh[b - 1];
  u32 total_all = sh[255];

  u32 sizes[8];
#pragma unroll
  for (int x = 0; x < 8; ++x) sizes[x] = min(cursor[(b * 8 + x) * 16], (u32)SUBCAP);

#pragma unroll
  for (int x = 0; x < 8; ++x) {
    const u32* sp = subb + (size_t)(b * 8 + x) * SUBCAP;
    u32 s = sizes[x];
    for (u32 i = t; i < s; i += 256)
      atomicAdd(&cnt[sp[i] >> 16], 1u);
  }
  __syncthreads();

  u32 c  = cnt[t];
  u32 dc = min(c, 63u);
  atomicAdd(&hist[dc], 1u);                    // degree histogram (pre-scan)
  sh[t] = c;
  __syncthreads();
  for (int off = 1; off < 256; off <<= 1) {
    u32 v = sh[t]; u32 a = (t >= off) ? sh[t - off] : 0u;
    __syncthreads(); sh[t] = v + a; __syncthreads();
  }
  u32 loc = sh[t] - c;
  rowptr[b * 256 + t] = base + loc;
  cur[t] = loc;
  if (b == 255 && t == 255) rowptr[NN] = total_all;
  __syncthreads();
  if (t == 0) {                                // exclusive scan of hist
    u32 run = 0;
    for (int i = 0; i < 64; ++i) { u32 h = hist[i]; hist[i] = run; run += h; }
  }
  __syncthreads();
  u32 r = atomicAdd(&hist[dc], 1u);            // rank within bucket by degree
  perm[b * 256 + r] = b * 256 + t;
  __syncthreads();

#pragma unroll
  for (int x = 0; x < 8; ++x) {
    const u32* sp = subb + (size_t)(b * 8 + x) * SUBCAP;
    u32 s = sizes[x];
    for (u32 i = t; i < s; i += 256) {
      u32 en = sp[i];
      u32 pos = atomicAdd(&cur[en >> 16], 1u);
      csr[base + pos] = (u16)(en & 0xFFFFu);
    }
  }
}

// ---------------- Fused attention + aggregation (no-max softmax) ------------
// Quarter-wave (16 lanes) per dst node, nodes taken via degree-sorted perm.
// Edge loop unrolled x4 -> 16 row-gathers in flight per wave.
__device__ __forceinline__ void gat_item(u32x4 xw, const f32x2* av, const f32x2* rv,
                                         float& l, f32x2* acc)
{
  f32x2 xv[4];
  f32x2 sc2 = {0.f, 0.f};
#pragma unroll
  for (int i = 0; i < 4; ++i) {
    xv[i] = bfp2f(xw[i]);
    f32x2 t = xv[i] + rv[i];
    f32x2 lr = pk_max(t, t * NEG_SLOPE);        // leaky_relu
    sc2 += av[i] * lr;
  }
  float partial = sc2.x + sc2.y;
  partial += __shfl_xor(partial, 1);
  partial += __shfl_xor(partial, 2);
  partial += __shfl_xor(partial, 4);            // per-head score (8-lane group)
  float p = __expf(partial);
  l += p;
#pragma unroll
  for (int i = 0; i < 4; ++i) acc[i] += p * xv[i];
}

__global__ __launch_bounds__(256) void gat_fused(
    const u16* __restrict__ xl, const u16* __restrict__ xr,
    const u32* __restrict__ rowptr, const u16* __restrict__ csr,
    const u32* __restrict__ perm,
    const float* __restrict__ att, const float* __restrict__ bias,
    float* __restrict__ out)
{
  int tid  = threadIdx.x;
  int node = (int)perm[blockIdx.x * 16 + (tid >> 4)];
  int q    = tid & 15;
  int c0   = q * 8;

  f32x2 av[4], rv[4];
  {
    f32x4 a0 = *(const f32x4*)(att + c0);
    f32x4 a1 = *(const f32x4*)(att + c0 + 4);
    av[0].x = a0[0]; av[0].y = a0[1]; av[1].x = a0[2]; av[1].y = a0[3];
    av[2].x = a1[0]; av[2].y = a1[1]; av[3].x = a1[2]; av[3].y = a1[3];
    u32x4 rw = *(const u32x4*)(xr + (size_t)node * DDIM + c0);
#pragma unroll
    for (int i = 0; i < 4; ++i) rv[i] = bfp2f(rw[i]);
  }

  float l = 0.f;
  f32x2 acc[4] = { {0,0},{0,0},{0,0},{0,0} };

  u32 rs    = rowptr[node];
  int total = (int)(rowptr[node + 1] - rs) + 1;   // item 0 = self loop

  int j = 0;
  for (; j + 4 <= total; j += 4) {
    u32 s0 = (j == 0) ? (u32)node : (u32)csr[rs + j - 1];
    u32 s1 = (u32)csr[rs + j + 0];
    u32 s2 = (u32)csr[rs + j + 1];
    u32 s3 = (u32)csr[rs + j + 2];
    u32x4 x0 = *(const u32x4*)(xl + (size_t)s0 * DDIM + c0);
    u32x4 x1 = *(const u32x4*)(xl + (size_t)s1 * DDIM + c0);
    u32x4 x2 = *(const u32x4*)(xl + (size_t)s2 * DDIM + c0);
    u32x4 x3 = *(const u32x4*)(xl + (size_t)s3 * DDIM + c0);
    gat_item(x0, av, rv, l, acc);
    gat_item(x1, av, rv, l, acc);
    gat_item(x2, av, rv, l, acc);
    gat_item(x3, av, rv, l, acc);
  }
  for (; j < total; ++j) {
    u32 s = (j == 0) ? (u32)node : (u32)csr[rs + j - 1];
    u32x4 xw = *(const u32x4*)(xl + (size_t)s * DDIM + c0);
    gat_item(xw, av, rv, l, acc);
  }

  float inv = 1.f / l;
  f32x4 o0, o1;
  o0[0] = fmaf(acc[0].x, inv, bias[c0 + 0]);
  o0[1] = fmaf(acc[0].y, inv, bias[c0 + 1]);
  o0[2] = fmaf(acc[1].x, inv, bias[c0 + 2]);
  o0[3] = fmaf(acc[1].y, inv, bias[c0 + 3]);
  o1[0] = fmaf(acc[2].x, inv, bias[c0 + 4]);
  o1[1] = fmaf(acc[2].y, inv, bias[c0 + 5]);
  o1[2] = fmaf(acc[3].x, inv, bias[c0 + 6]);
  o1[3] = fmaf(acc[3].y, inv, bias[c0 + 7]);
  float* op = out + (size_t)node * DDIM + c0;
  *(f32x4*)op       = o0;
  *(f32x4*)(op + 4) = o1;
}

// ---------------- launch ----------------
extern "C" void kernel_launch(void* const* d_in, const int* in_sizes, int n_in,
                              void* d_out, int out_size, void* d_ws, size_t ws_size,
                              hipStream_t stream) {
  (void)in_sizes; (void)n_in; (void)out_size; (void)ws_size;
  const float* x    = (const float*)d_in[0];  // [N,128] fp32
  const int*   ei   = (const int*)d_in[1];    // [2,E] int64/int32 (detected)
  const float* Wl   = (const float*)d_in[2];  // [128,128] fp32
  const float* Wr   = (const float*)d_in[3];
  const float* attw = (const float*)d_in[4];  // [2,64] fp32
  const float* bias = (const float*)d_in[5];  // [128] fp32
  float* out = (float*)d_out;                 // [N,128] fp32

  char* w = (char*)d_ws;
  u16* xl     = (u16*)(w);                              // 16 MB
  u16* xr     = (u16*)(w + (16u << 20));                // 16 MB
  u32* subb   = (u32*)(w + (32u << 20));                // 6 MB
  u32* cursor = (u32*)(w + (38u << 20));                // 128 KB
  u32* mode   = (u32*)(w + (38u << 20) + (192u << 10)); // 8 B
  u32* rowptr = (u32*)(w + (38u << 20) + (256u << 10)); // 256 KB + 4
  u16* csr    = (u16*)(w + (39u << 20));                // 2 MB
  u16* wpack  = (u16*)(w + (41u << 20));                // 64 KB
  u32* perm   = (u32*)(w + (41u << 20) + (128u << 10)); // 256 KB

  init_misc<<<10, 256, 0, stream>>>(ei, mode, Wl, Wr, wpack, cursor);
  pass1_bin<<<EE / 512, 256, 0, stream>>>(ei, cursor, subb, mode);
  gemm_xlxr<<<NN / 16, 256, 0, stream>>>(x, wpack, xl, xr);
  pass2_build<<<256, 256, 0, stream>>>(cursor, subb, rowptr, csr, perm);
  gat_fused<<<NN / 16, 256, 0, stream>>>(xl, xr, rowptr, csr, perm, attw, bias, out);
}

// Round 9
// 232.305 us; speedup vs baseline: 1.0725x; 1.0725x over previous
//
#include <hip/hip_runtime.h>

typedef unsigned short u16;
typedef unsigned int   u32;

#define NN     65536      // nodes = B*L = 8*8192
#define DDIM   128        // feature dim = H*C
#define EE     1048576    // edges (self loop handled inline, not in CSR)
#define NEG_SLOPE 0.2f
#define SUBCAP 768        // per (bucket, xcd-slot) capacity; mean 512

typedef __attribute__((ext_vector_type(8))) short          short8;
typedef __attribute__((ext_vector_type(2))) float          f32x2;
typedef __attribute__((ext_vector_type(4))) float          f32x4;
typedef __attribute__((ext_vector_type(4))) u32            u32x4;

__device__ __forceinline__ float bf2f(u16 b) { return __uint_as_float(((u32)b) << 16); }
__device__ __forceinline__ u16 f2bf(float f) {
  u32 u = __float_as_uint(f);
  u += 0x7FFFu + ((u >> 16) & 1u);   // round-to-nearest-even
  return (u16)(u >> 16);
}
__device__ __forceinline__ f32x2 bfp2f(u32 w) {
  f32x2 r;
  r.x = __uint_as_float(w << 16);
  r.y = __uint_as_float(w & 0xFFFF0000u);
  return r;
}
__device__ __forceinline__ f32x2 pk_max(f32x2 a, f32x2 b) {
  f32x2 r; r.x = fmaxf(a.x, b.x); r.y = fmaxf(a.y, b.y); return r;
}

// ---- init: b0 = dtype detect; b1..b8 = W pack (parallel); b9..b16 = cursors -
__global__ void init_misc(const int* __restrict__ ei, u32* __restrict__ mode,
                          const float* __restrict__ Wl, const float* __restrict__ Wr,
                          u16* __restrict__ wpack, u32* __restrict__ cursor) {
  int t = threadIdx.x, b = blockIdx.x;
  if (b == 0) {
    if (t < 64) {
      int nz = (ei[2 * t + 1] != 0) ? 1 : 0;   // int64 storage => high words zero
      unsigned long long bal = __ballot(nz);
      if (t == 0) mode[0] = (bal == 0ull) ? 1u : 0u;   // 1 = int64
    }
    return;
  }
  if (b <= 8) {
    // one block per (colhalf, ks); 256 threads = 4 p-groups x 64 lanes; 2 p iters
    int pb = b - 1;
    int colhalf = pb >> 2, ks = pb & 3;
    int lane = t & 63, pp = t >> 6;
    int m16 = lane & 15, quad = lane >> 4;
#pragma unroll
    for (int pq = 0; pq < 2; ++pq) {
      int p = pq * 4 + pp;                     // 0..3 = Wl ct, 4..7 = Wr ct
      const float* W = (p < 4) ? Wl : Wr;
      int n = colhalf * 64 + (p & 3) * 16 + m16;
#pragma unroll
      for (int j = 0; j < 8; ++j) {
        int k = ks * 32 + quad * 8 + j;
        wpack[(((((colhalf * 4 + ks) * 8) + p) * 64 + lane) * 8) + j] = f2bf(W[k * DDIM + n]);
      }
    }
    return;
  }
  // b = 9..16: zero cursor lines (2048 sub-buckets x 16 u32)
  int i = (b - 9) * 256 + t;
#pragma unroll
  for (int k = 0; k < 16; ++k) cursor[i * 16 + k] = 0;
}

// ---------------- GEMM: xl = x@Wl, xr = x@Wr (bf16 MFMA, fp32 in, bf16 out) -
// 1024 blocks x 64 rows. Wave w: matrix = w>>1, colhalf = w&1 (16 frags, ~110
// VGPR -> 4 waves/SIMD). All 4 waves read the same 32 KB of A (L1 reuse x4);
// W preamble amortized over 64 MFMAs via the rt x4 loop.
__global__ __launch_bounds__(256) void gemm_xlxr(
    const float* __restrict__ x, const u16* __restrict__ wpack,
    u16* __restrict__ xl, u16* __restrict__ xr)
{
  int tid  = threadIdx.x;
  int wave = tid >> 6;
  int lane = tid & 63;
  int m16  = lane & 15;
  int quad = lane >> 4;
  int mat     = wave >> 1;     // 0 = Wl -> xl, 1 = Wr -> xr
  int colhalf = wave & 1;
  int rowbase = blockIdx.x * 64;

  const u16* wp = wpack + (size_t)colhalf * (4 * 8 * 64 * 8);
  short8 bfr[4][4];
#pragma unroll
  for (int ks = 0; ks < 4; ++ks)
#pragma unroll
    for (int ct = 0; ct < 4; ++ct)
      bfr[ks][ct] = *(const short8*)(wp + ((size_t)(ks * 8 + mat * 4 + ct) * 64 + lane) * 8);

  u16* outp = mat ? xr : xl;
#pragma unroll
  for (int rt = 0; rt < 4; ++rt) {
    int r0 = rowbase + rt * 16;
    f32x4 acc[4] = { {0,0,0,0},{0,0,0,0},{0,0,0,0},{0,0,0,0} };
#pragma unroll
    for (int ks = 0; ks < 4; ++ks) {
      const float* ap = x + (size_t)(r0 + m16) * DDIM + ks * 32 + quad * 8;
      f32x4 a0 = *(const f32x4*)ap;
      f32x4 a1 = *(const f32x4*)(ap + 4);
      short8 a;
#pragma unroll
      for (int c = 0; c < 4; ++c) { a[c] = (short)f2bf(a0[c]); a[4 + c] = (short)f2bf(a1[c]); }
#pragma unroll
      for (int ct = 0; ct < 4; ++ct)
        acc[ct] = __builtin_amdgcn_mfma_f32_16x16x32_bf16(a, bfr[ks][ct], acc[ct], 0, 0, 0);
    }
#pragma unroll
    for (int ct = 0; ct < 4; ++ct) {
      int c = colhalf * 64 + ct * 16 + m16;
#pragma unroll
      for (int rg = 0; rg < 4; ++rg) {
        int r = r0 + quad * 4 + rg;
        outp[(size_t)r * DDIM + c] = f2bf(acc[ct][rg]);
      }
    }
  }
}

// ---------------- CSR build: two-level counting sort ------------------------
// pass1: 4 edges/thread, 16B index loads; bin by dst>>8 into 256 buckets x 8
// XCD-local slots (blockIdx&7 ~ XCD via round-robin dispatch).
__global__ __launch_bounds__(256) void pass1_bin(const int* __restrict__ ei,
                                                 u32* __restrict__ cursor,
                                                 u32* __restrict__ subb,
                                                 const u32* __restrict__ mode)
{
  int base = (blockIdx.x * 256 + threadIdx.x) * 4;   // grid covers EE/4 exactly
  int s[4], d[4];
  if (mode[0]) {
    const long long* ei64 = (const long long*)ei;
    longlong2 sa = *(const longlong2*)(ei64 + base);
    longlong2 sb = *(const longlong2*)(ei64 + base + 2);
    longlong2 da = *(const longlong2*)(ei64 + EE + base);
    longlong2 db = *(const longlong2*)(ei64 + EE + base + 2);
    s[0] = (int)sa.x; s[1] = (int)sa.y; s[2] = (int)sb.x; s[3] = (int)sb.y;
    d[0] = (int)da.x; d[1] = (int)da.y; d[2] = (int)db.x; d[3] = (int)db.y;
  } else {
    int4 sv = *(const int4*)(ei + base);
    int4 dv = *(const int4*)(ei + EE + base);
    s[0] = sv.x; s[1] = sv.y; s[2] = sv.z; s[3] = sv.w;
    d[0] = dv.x; d[1] = dv.y; d[2] = dv.z; d[3] = dv.w;
  }
  int x = blockIdx.x & 7;
#pragma unroll
  for (int i = 0; i < 4; ++i) {
    int sb_ = (d[i] >> 8) * 8 + x;
    u32 p = atomicAdd(&cursor[sb_ * 16], 1u);
    if (p < SUBCAP) subb[(size_t)sb_ * SUBCAP + p] = ((u32)(d[i] & 255) << 16) | (u32)s[i];
  }
}

// pass2: one block per bucket; integrated bucket-total scan, LDS count+scan
// of 256 dsts, coalesced rowptr write, u16 src placement, degree-ranked perm.
__global__ __launch_bounds__(256) void pass2_build(const u32* __restrict__ cursor,
                                                   const u32* __restrict__ subb,
                                                   u32* __restrict__ rowptr,
                                                   u16* __restrict__ csr,
                                                   u32* __restrict__ perm)
{
  __shared__ u32 sh[256];
  __shared__ u32 cnt[256];
  __shared__ u32 cur[256];
  __shared__ u32 hist[64];
  int b = blockIdx.x, t = threadIdx.x;

  u32 tot = 0;
#pragma unroll
  for (int x = 0; x < 8; ++x) tot += min(cursor[(t * 8 + x) * 16], (u32)SUBCAP);
  sh[t] = tot; cnt[t] = 0;
  if (t < 64) hist[t] = 0;
  __syncthreads();
  for (int off = 1; off < 256; off <<= 1) {
    u32 v = sh[t]; u32 a = (t >= off) ? sh[t - off] : 0u;
    __syncthreads(); sh[t] = v + a; __syncthreads();
  }
  u32 base      = (b == 0) ? 0u : sh[b - 1];
  u32 total_all = sh[255];

  u32 sizes[8];
#pragma unroll
  for (int x = 0; x < 8; ++x) sizes[x] = min(cursor[(b * 8 + x) * 16], (u32)SUBCAP);

#pragma unroll
  for (int x = 0; x < 8; ++x) {
    const u32* sp = subb + (size_t)(b * 8 + x) * SUBCAP;
    u32 s = sizes[x];
    for (u32 i = t; i < s; i += 256)
      atomicAdd(&cnt[sp[i] >> 16], 1u);
  }
  __syncthreads();

  u32 c  = cnt[t];
  u32 dc = min(c, 63u);
  atomicAdd(&hist[dc], 1u);                    // degree histogram
  sh[t] = c;
  __syncthreads();
  for (int off = 1; off < 256; off <<= 1) {
    u32 v = sh[t]; u32 a = (t >= off) ? sh[t - off] : 0u;
    __syncthreads(); sh[t] = v + a; __syncthreads();
  }
  u32 loc = sh[t] - c;
  rowptr[b * 256 + t] = base + loc;
  cur[t] = loc;
  if (b == 255 && t == 255) rowptr[NN] = total_all;
  __syncthreads();
  if (t == 0) {
    u32 run = 0;
    for (int i = 0; i < 64; ++i) { u32 h = hist[i]; hist[i] = run; run += h; }
  }
  __syncthreads();
  u32 r = atomicAdd(&hist[dc], 1u);            // rank within bucket by degree
  perm[b * 256 + r] = b * 256 + t;
  __syncthreads();

#pragma unroll
  for (int x = 0; x < 8; ++x) {
    const u32* sp = subb + (size_t)(b * 8 + x) * SUBCAP;
    u32 s = sizes[x];
    for (u32 i = t; i < s; i += 256) {
      u32 en = sp[i];
      u32 pos = atomicAdd(&cur[en >> 16], 1u);
      csr[base + pos] = (u16)(en & 0xFFFFu);
    }
  }
}

// ---------------- Fused attention + aggregation (no-max softmax) ------------
// Quarter-wave (16 lanes) per dst node, nodes via degree-sorted perm.
// Edge loop unrolled x4 -> 16 row-gathers in flight per wave.
__device__ __forceinline__ void gat_item(u32x4 xw, const f32x2* av, const f32x2* rv,
                                         float& l, f32x2* acc)
{
  f32x2 xv[4];
  f32x2 sc2 = {0.f, 0.f};
#pragma unroll
  for (int i = 0; i < 4; ++i) {
    xv[i] = bfp2f(xw[i]);
    f32x2 t = xv[i] + rv[i];
    f32x2 lr = pk_max(t, t * NEG_SLOPE);        // leaky_relu
    sc2 += av[i] * lr;
  }
  float partial = sc2.x + sc2.y;
  partial += __shfl_xor(partial, 1);
  partial += __shfl_xor(partial, 2);
  partial += __shfl_xor(partial, 4);            // per-head score (8-lane group)
  float p = __expf(partial);
  l += p;
#pragma unroll
  for (int i = 0; i < 4; ++i) acc[i] += p * xv[i];
}

__global__ __launch_bounds__(256) void gat_fused(
    const u16* __restrict__ xl, const u16* __restrict__ xr,
    const u32* __restrict__ rowptr, const u16* __restrict__ csr,
    const u32* __restrict__ perm,
    const float* __restrict__ att, const float* __restrict__ bias,
    float* __restrict__ out)
{
  int tid  = threadIdx.x;
  int node = (int)perm[blockIdx.x * 16 + (tid >> 4)];
  int q    = tid & 15;
  int c0   = q * 8;

  f32x2 av[4], rv[4];
  {
    f32x4 a0 = *(const f32x4*)(att + c0);
    f32x4 a1 = *(const f32x4*)(att + c0 + 4);
    av[0].x = a0[0]; av[0].y = a0[1]; av[1].x = a0[2]; av[1].y = a0[3];
    av[2].x = a1[0]; av[2].y = a1[1]; av[3].x = a1[2]; av[3].y = a1[3];
    u32x4 rw = *(const u32x4*)(xr + (size_t)node * DDIM + c0);
#pragma unroll
    for (int i = 0; i < 4; ++i) rv[i] = bfp2f(rw[i]);
  }

  float l = 0.f;
  f32x2 acc[4] = { {0,0},{0,0},{0,0},{0,0} };

  u32 rs    = rowptr[node];
  int total = (int)(rowptr[node + 1] - rs) + 1;   // item 0 = self loop

  int j = 0;
  for (; j + 4 <= total; j += 4) {
    u32 s0 = (j == 0) ? (u32)node : (u32)csr[rs + j - 1];
    u32 s1 = (u32)csr[rs + j + 0];
    u32 s2 = (u32)csr[rs + j + 1];
    u32 s3 = (u32)csr[rs + j + 2];
    u32x4 x0 = *(const u32x4*)(xl + (size_t)s0 * DDIM + c0);
    u32x4 x1 = *(const u32x4*)(xl + (size_t)s1 * DDIM + c0);
    u32x4 x2 = *(const u32x4*)(xl + (size_t)s2 * DDIM + c0);
    u32x4 x3 = *(const u32x4*)(xl + (size_t)s3 * DDIM + c0);
    gat_item(x0, av, rv, l, acc);
    gat_item(x1, av, rv, l, acc);
    gat_item(x2, av, rv, l, acc);
    gat_item(x3, av, rv, l, acc);
  }
  for (; j < total; ++j) {
    u32 s = (j == 0) ? (u32)node : (u32)csr[rs + j - 1];
    u32x4 xw = *(const u32x4*)(xl + (size_t)s * DDIM + c0);
    gat_item(xw, av, rv, l, acc);
  }

  float inv = 1.f / l;
  f32x4 o0, o1;
  o0[0] = fmaf(acc[0].x, inv, bias[c0 + 0]);
  o0[1] = fmaf(acc[0].y, inv, bias[c0 + 1]);
  o0[2] = fmaf(acc[1].x, inv, bias[c0 + 2]);
  o0[3] = fmaf(acc[1].y, inv, bias[c0 + 3]);
  o1[0] = fmaf(acc[2].x, inv, bias[c0 + 4]);
  o1[1] = fmaf(acc[2].y, inv, bias[c0 + 5]);
  o1[2] = fmaf(acc[3].x, inv, bias[c0 + 6]);
  o1[3] = fmaf(acc[3].y, inv, bias[c0 + 7]);
  float* op = out + (size_t)node * DDIM + c0;
  *(f32x4*)op       = o0;
  *(f32x4*)(op + 4) = o1;
}

// ---------------- launch ----------------
extern "C" void kernel_launch(void* const* d_in, const int* in_sizes, int n_in,
                              void* d_out, int out_size, void* d_ws, size_t ws_size,
                              hipStream_t stream) {
  (void)in_sizes; (void)n_in; (void)out_size; (void)ws_size;
  const float* x    = (const float*)d_in[0];  // [N,128] fp32
  const int*   ei   = (const int*)d_in[1];    // [2,E] int64/int32 (detected)
  const float* Wl   = (const float*)d_in[2];  // [128,128] fp32
  const float* Wr   = (const float*)d_in[3];
  const float* attw = (const float*)d_in[4];  // [2,64] fp32
  const float* bias = (const float*)d_in[5];  // [128] fp32
  float* out = (float*)d_out;                 // [N,128] fp32

  char* w = (char*)d_ws;
  u16* xl     = (u16*)(w);                              // 16 MB
  u16* xr     = (u16*)(w + (16u << 20));                // 16 MB
  u32* subb   = (u32*)(w + (32u << 20));                // 6 MB
  u32* cursor = (u32*)(w + (38u << 20));                // 128 KB
  u32* mode   = (u32*)(w + (38u << 20) + (192u << 10)); // 8 B
  u32* rowptr = (u32*)(w + (38u << 20) + (256u << 10)); // 256 KB + 4
  u16* csr    = (u16*)(w + (39u << 20));                // 2 MB
  u16* wpack  = (u16*)(w + (41u << 20));                // 64 KB
  u32* perm   = (u32*)(w + (41u << 20) + (128u << 10)); // 256 KB

  init_misc<<<17, 256, 0, stream>>>(ei, mode, Wl, Wr, wpack, cursor);
  pass1_bin<<<EE / 1024, 256, 0, stream>>>(ei, cursor, subb, mode);
  gemm_xlxr<<<NN / 64, 256, 0, stream>>>(x, wpack, xl, xr);
  pass2_build<<<256, 256, 0, stream>>>(cursor, subb, rowptr, csr, perm);
  gat_fused<<<NN / 16, 256, 0, stream>>>(xl, xr, rowptr, csr, perm, attw, bias, out);
}